// Round 16
// baseline (328.124 us; speedup 1.0000x reference)
//
#include <hip/hip_runtime.h>

#define T2 128
#define NB 16
#define LOG2E 1.44269504088896340736f
#define LN2   0.69314718055994530942f

typedef _Float16 f16;
typedef __attribute__((ext_vector_type(2))) _Float16 f16x2;
typedef __attribute__((ext_vector_type(8))) _Float16 f16x8;
typedef __attribute__((ext_vector_type(4))) float f32x4;

__device__ __forceinline__ unsigned pkrtz(float a, float b) {
  return __builtin_bit_cast(unsigned, __builtin_amdgcn_cvt_pkrtz(a, b));
}
__device__ __forceinline__ unsigned pkmul(unsigned a, unsigned b) {
  return __builtin_bit_cast(unsigned,
      (f16x2)(__builtin_bit_cast(f16x2, a) * __builtin_bit_cast(f16x2, b)));
}
__device__ __forceinline__ float ex2(float x) { return __builtin_amdgcn_exp2f(x); }
__device__ __forceinline__ float lg2(float x) { return __builtin_amdgcn_logf(x); }
__device__ __forceinline__ f16x8 u4f(uint4 u) { return __builtin_bit_cast(f16x8, u); }
__device__ __forceinline__ float lo(unsigned u) {
  return (float)__builtin_bit_cast(f16x2, u).x;
}
__device__ __forceinline__ float hi(unsigned u) {
  return (float)__builtin_bit_cast(f16x2, u).y;
}

#define MF(Aa, Bb, Cc) __builtin_amdgcn_mfma_f32_16x16x32_f16(Aa, Bb, Cc, 0, 0, 0)
#define SGB(MASK_, N_) __builtin_amdgcn_sched_group_barrier(MASK_, N_, 0)

// ---- kernel 1: exp pass, rho-permuted slot order (r12-validated).
__global__ __launch_bounds__(256)
void crf_expf(const float* __restrict__ feats, unsigned* __restrict__ efp,
              long long n2) {
  long long i = (long long)blockIdx.x * 256 + threadIdx.x;
  if (i >= n2) return;
  int r  = (int)(i & 31);
  int g  = r >> 3;
  int mt = r & 7;
  long long bt = i >> 5;  // b*S + t
  const float* f = feats + bt * T2 + 32 * (mt >> 1) + 8 * g + 4 * (mt & 1);
  float4 v = *(const float4*)f;
  uint2 o;
  o.x = pkrtz(ex2(v.x * LOG2E), ex2(v.y * LOG2E));
  o.y = pkrtz(ex2(v.z * LOG2E), ex2(v.w * LOG2E));
  *(uint2*)(efp + bt * 64 + 16 * g + 2 * mt) = o;
}

// ---- kernel 2: fwd-bwd split (r14, 229us base) + sched_group_barrier
// pinned interleave: [VMEM x4][MFMA x28][(VALU x8, MFMA x1) x4][VALU x32].
// Theory: the ~550cy/step stall = 16 pack-points x ~35cy MFMA->VALU result
// latency, serially exposed because the compiler schedules packs right
// behind their producer MFMAs. Lagged packs (>=4 MFMAs distance) + SGB
// should hide it and approach the 515cy/step MFMA-pipe floor.
__global__ __launch_bounds__(128, 1)
void crf_scan(const unsigned* __restrict__ efp, const float* __restrict__ trans,
              float* __restrict__ out, int S) {
  const int tid = threadIdx.x;
  const int wid = tid >> 6;
  const int l   = tid & 63;
  const int c = l & 15, g = l >> 4;
  const int b0 = blockIdx.x * NB;
  const int HS = S >> 1;  // 512

  __shared__ uint4 xw[64][4];
  __shared__ float xacc[16];

  const unsigned* efb = efp + (size_t)(b0 + c) * S * 64 + (size_t)g * 16;

  f16x8 A[8][4];
  uint4 qa0, qa1, qa2, qa3;
  uint4 qb0 = make_uint4(0,0,0,0), qb1 = qb0, qb2 = qb0, qb3 = qb0;
  uint4 f0a, f0b, f0c, f0d, f1a, f1b, f1c, f1d;
  uint4 f2a, f2b, f2c, f2d, f3a, f3b, f3c, f3d;
  float log2acc = 0.f;

  if (wid == 0) {
    // forward A (rho rows, k cols raw), damped
#pragma unroll
    for (int mt = 0; mt < 8; ++mt) {
      const int prow = 32 * (mt >> 1) + 8 * (c >> 2) + 4 * (mt & 1) + (c & 3);
#pragma unroll
      for (int kk = 0; kk < 4; ++kk) {
        const float* r = trans + (size_t)prow * T2 + 32 * kk + 8 * g;
        float4 u0 = *(const float4*)r;
        float4 u1 = *(const float4*)(r + 4);
        f16x8 a;
        a[0] = (f16)ex2(fmaf(u0.x, LOG2E, -8.f));
        a[1] = (f16)ex2(fmaf(u0.y, LOG2E, -8.f));
        a[2] = (f16)ex2(fmaf(u0.z, LOG2E, -8.f));
        a[3] = (f16)ex2(fmaf(u0.w, LOG2E, -8.f));
        a[4] = (f16)ex2(fmaf(u1.x, LOG2E, -8.f));
        a[5] = (f16)ex2(fmaf(u1.y, LOG2E, -8.f));
        a[6] = (f16)ex2(fmaf(u1.z, LOG2E, -8.f));
        a[7] = (f16)ex2(fmaf(u1.w, LOG2E, -8.f));
        A[mt][kk] = a;
      }
    }
    qa0 = make_uint4(0,0,0,0); qa1 = qa0; qa2 = qa0; qa3 = qa0;
    qa3.w = (g == 3) ? 0x3C000000u : 0u;  // onehot at k=127
    f0a = *(const uint4*)(efb + 0);   f0b = *(const uint4*)(efb + 4);
    f0c = *(const uint4*)(efb + 8);   f0d = *(const uint4*)(efb + 12);
    f1a = *(const uint4*)(efb + 64);  f1b = *(const uint4*)(efb + 68);
    f1c = *(const uint4*)(efb + 72);  f1d = *(const uint4*)(efb + 76);
    f2a = *(const uint4*)(efb + 128); f2b = *(const uint4*)(efb + 132);
    f2c = *(const uint4*)(efb + 136); f2d = *(const uint4*)(efb + 140);
    f3a = *(const uint4*)(efb + 192); f3b = *(const uint4*)(efb + 196);
    f3c = *(const uint4*)(efb + 200); f3d = *(const uint4*)(efb + 204);
  } else {
    // backward A = E^T: element (prow, kcol) = exp2(trans[kcol][prow]*L2E-8)
#pragma unroll
    for (int mt = 0; mt < 8; ++mt) {
      const int prow = 32 * (mt >> 1) + 8 * (c >> 2) + 4 * (mt & 1) + (c & 3);
#pragma unroll
      for (int kk = 0; kk < 4; ++kk) {
        f16x8 a;
#pragma unroll
        for (int j = 0; j < 8; ++j)
          a[j] = (f16)ex2(fmaf(trans[(size_t)(32 * kk + 8 * g + j) * T2 + prow],
                               LOG2E, -8.f));
        A[mt][kk] = a;
      }
    }
    // initial frag = pk(eend) * EF[S-1]
    const float* te = trans + (size_t)(T2 - 2) * T2;
    const unsigned* e9 = efb + (size_t)(S - 1) * 64;
    uint4 E9a = *(const uint4*)(e9);     uint4 E9b = *(const uint4*)(e9 + 4);
    uint4 E9c = *(const uint4*)(e9 + 8); uint4 E9d = *(const uint4*)(e9 + 12);
#define EEW(kk, j2) pkrtz(ex2(te[32*(kk) + 8*g + 2*(j2)] * LOG2E),             \
                          ex2(te[32*(kk) + 8*g + 2*(j2) + 1] * LOG2E))
    qa0.x = pkmul(EEW(0,0), E9a.x); qa0.y = pkmul(EEW(0,1), E9a.y);
    qa0.z = pkmul(EEW(0,2), E9a.z); qa0.w = pkmul(EEW(0,3), E9a.w);
    qa1.x = pkmul(EEW(1,0), E9b.x); qa1.y = pkmul(EEW(1,1), E9b.y);
    qa1.z = pkmul(EEW(1,2), E9b.z); qa1.w = pkmul(EEW(1,3), E9b.w);
    qa2.x = pkmul(EEW(2,0), E9c.x); qa2.y = pkmul(EEW(2,1), E9c.y);
    qa2.z = pkmul(EEW(2,2), E9c.z); qa2.w = pkmul(EEW(2,3), E9c.w);
    qa3.x = pkmul(EEW(3,0), E9d.x); qa3.y = pkmul(EEW(3,1), E9d.y);
    qa3.z = pkmul(EEW(3,2), E9d.z); qa3.w = pkmul(EEW(3,3), E9d.w);
#undef EEW
    const unsigned* p0 = efb + (size_t)(S - 2) * 64;
    const unsigned* p1 = efb + (size_t)(S - 3) * 64;
    const unsigned* p2 = efb + (size_t)(S - 4) * 64;
    const unsigned* p3 = efb + (size_t)(S - 5) * 64;
    f0a = *(const uint4*)(p0); f0b = *(const uint4*)(p0+4);
    f0c = *(const uint4*)(p0+8); f0d = *(const uint4*)(p0+12);
    f1a = *(const uint4*)(p1); f1b = *(const uint4*)(p1+4);
    f1c = *(const uint4*)(p1+8); f1d = *(const uint4*)(p1+12);
    f2a = *(const uint4*)(p2); f2b = *(const uint4*)(p2+4);
    f2c = *(const uint4*)(p2+8); f2d = *(const uint4*)(p2+12);
    f3a = *(const uint4*)(p3); f3b = *(const uint4*)(p3+4);
    f3c = *(const uint4*)(p3+8); f3d = *(const uint4*)(p3+12);
  }

#define PK2(MM, NN, W0_, W1_, E0_, E1_)                                        \
    W0_ = pkmul(pkrtz(MM[0] + NN[0], MM[1] + NN[1]), E0_);                     \
    W1_ = pkmul(pkrtz(MM[2] + NN[2], MM[3] + NN[3]), E1_);

#define STEPM(RELREC, DORESC, P0,P1,P2,P3, N0,N1,N2,N3, CA,CB,CC,CD,           \
              GA,GB,GC,GD)                                                     \
  {                                                                            \
    f16x8 B0 = u4f(P0), B1 = u4f(P1), B2 = u4f(P2), B3 = u4f(P3);              \
    f32x4 z = {0.f, 0.f, 0.f, 0.f};                                            \
    f32x4 m0,m1,m2,m3,m4,m5,m6,m7, n0,n1,n2,n3,n4,n5,n6,n7;                    \
    m0 = MF(A[0][0],B0,z); m1 = MF(A[1][0],B0,z);                              \
    m2 = MF(A[2][0],B0,z); m3 = MF(A[3][0],B0,z);                              \
    m4 = MF(A[4][0],B0,z); m5 = MF(A[5][0],B0,z);                              \
    m6 = MF(A[6][0],B0,z); m7 = MF(A[7][0],B0,z);                              \
    n0 = MF(A[0][1],B1,z); n1 = MF(A[1][1],B1,z);                              \
    n2 = MF(A[2][1],B1,z); n3 = MF(A[3][1],B1,z);                              \
    n4 = MF(A[4][1],B1,z); n5 = MF(A[5][1],B1,z);                              \
    n6 = MF(A[6][1],B1,z); n7 = MF(A[7][1],B1,z);                              \
    m0 = MF(A[0][2],B2,m0); m1 = MF(A[1][2],B2,m1);                            \
    m2 = MF(A[2][2],B2,m2); m3 = MF(A[3][2],B2,m3);                            \
    m4 = MF(A[4][2],B2,m4); m5 = MF(A[5][2],B2,m5);                            \
    m6 = MF(A[6][2],B2,m6); m7 = MF(A[7][2],B2,m7);                            \
    n0 = MF(A[0][3],B3,n0); n1 = MF(A[1][3],B3,n1);                            \
    n2 = MF(A[2][3],B3,n2); n3 = MF(A[3][3],B3,n3);                            \
    PK2(m0, n0, N0.x, N0.y, CA.x, CA.y)                                        \
    n4 = MF(A[4][3],B3,n4);                                                    \
    PK2(m1, n1, N0.z, N0.w, CA.z, CA.w)                                        \
    n5 = MF(A[5][3],B3,n5);                                                    \
    PK2(m2, n2, N1.x, N1.y, CB.x, CB.y)                                        \
    n6 = MF(A[6][3],B3,n6);                                                    \
    PK2(m3, n3, N1.z, N1.w, CB.z, CB.w)                                        \
    n7 = MF(A[7][3],B3,n7);                                                    \
    PK2(m4, n4, N2.x, N2.y, CC.x, CC.y)                                        \
    PK2(m5, n5, N2.z, N2.w, CC.z, CC.w)                                        \
    PK2(m6, n6, N3.x, N3.y, CD.x, CD.y)                                        \
    PK2(m7, n7, N3.z, N3.w, CD.z, CD.w)                                        \
    {                                                                          \
      const unsigned* p_ = efb + (size_t)(RELREC) * 64;                        \
      CA = *(const uint4*)(p_);      CB = *(const uint4*)(p_ + 4);             \
      CC = *(const uint4*)(p_ + 8);  CD = *(const uint4*)(p_ + 12);            \
    }                                                                          \
    SGB(0x20, 4);                       /* EF loads first (4-step slack) */    \
    SGB(0x8, 28);                       /* k0,k1,k2 + k3 lead n0..n3 */        \
    SGB(0x2, 8); SGB(0x8, 1);           /* PK0 || n4 */                        \
    SGB(0x2, 8); SGB(0x8, 1);           /* PK1 || n5 */                        \
    SGB(0x2, 8); SGB(0x8, 1);           /* PK2 || n6 */                        \
    SGB(0x2, 8); SGB(0x8, 1);           /* PK3 || n7 */                        \
    SGB(0x2, 32);                       /* PK4..PK7 */                         \
    if (DORESC) {                                                              \
      float s_ = lo(N0.x) + hi(N0.x) + lo(N0.y) + hi(N0.y)                     \
               + lo(N0.z) + hi(N0.z) + lo(N0.w) + hi(N0.w)                     \
               + lo(N1.x) + hi(N1.x) + lo(N1.y) + hi(N1.y)                     \
               + lo(N1.z) + hi(N1.z) + lo(N1.w) + hi(N1.w)                     \
               + lo(N2.x) + hi(N2.x) + lo(N2.y) + hi(N2.y)                     \
               + lo(N2.z) + hi(N2.z) + lo(N2.w) + hi(N2.w)                     \
               + lo(N3.x) + hi(N3.x) + lo(N3.y) + hi(N3.y)                     \
               + lo(N3.z) + hi(N3.z) + lo(N3.w) + hi(N3.w);                    \
      s_ += __shfl_xor(s_, 16);                                                \
      s_ += __shfl_xor(s_, 32);                                                \
      s_ = fmaxf(s_, 1e-30f);                                                  \
      float inv_ = 1.0f / s_;                                                  \
      unsigned ip_ = pkrtz(inv_, inv_);                                        \
      GA.x = pkmul(GA.x, ip_); GA.y = pkmul(GA.y, ip_);                        \
      GA.z = pkmul(GA.z, ip_); GA.w = pkmul(GA.w, ip_);                        \
      GB.x = pkmul(GB.x, ip_); GB.y = pkmul(GB.y, ip_);                        \
      GB.z = pkmul(GB.z, ip_); GB.w = pkmul(GB.w, ip_);                        \
      GC.x = pkmul(GC.x, ip_); GC.y = pkmul(GC.y, ip_);                        \
      GC.z = pkmul(GC.z, ip_); GC.w = pkmul(GC.w, ip_);                        \
      GD.x = pkmul(GD.x, ip_); GD.y = pkmul(GD.y, ip_);                        \
      GD.z = pkmul(GD.z, ip_); GD.w = pkmul(GD.w, ip_);                        \
      log2acc += lg2(s_);                                                      \
    }                                                                          \
  }

  if (wid == 0) {
    for (int t = 0; t < HS; t += 4) {
      STEPM((t+4 < HS ? t+4 : HS-1), ((t&7)==7),
            qa0,qa1,qa2,qa3, qb0,qb1,qb2,qb3,
            f0a,f0b,f0c,f0d, f1a,f1b,f1c,f1d)
      STEPM((t+5 < HS ? t+5 : HS-1), (((t+1)&7)==7),
            qb0,qb1,qb2,qb3, qa0,qa1,qa2,qa3,
            f1a,f1b,f1c,f1d, f2a,f2b,f2c,f2d)
      STEPM((t+6 < HS ? t+6 : HS-1), (((t+2)&7)==7),
            qa0,qa1,qa2,qa3, qb0,qb1,qb2,qb3,
            f2a,f2b,f2c,f2d, f3a,f3b,f3c,f3d)
      STEPM((t+7 < HS ? t+7 : HS-1), (((t+3)&7)==7 && t+3 != HS-1),
            qb0,qb1,qb2,qb3, qa0,qa1,qa2,qa3,
            f3a,f3b,f3c,f3d, f0a,f0b,f0c,f0d)
    }
  } else {
    for (int i = 0; i + 4 <= HS - 1; i += 4) {
      STEPM((S-2-(i+4) > HS ? S-2-(i+4) : HS), ((i&7)==7),
            qa0,qa1,qa2,qa3, qb0,qb1,qb2,qb3,
            f0a,f0b,f0c,f0d, f1a,f1b,f1c,f1d)
      STEPM((S-2-(i+5) > HS ? S-2-(i+5) : HS), (((i+1)&7)==7),
            qb0,qb1,qb2,qb3, qa0,qa1,qa2,qa3,
            f1a,f1b,f1c,f1d, f2a,f2b,f2c,f2d)
      STEPM((S-2-(i+6) > HS ? S-2-(i+6) : HS), (((i+2)&7)==7),
            qa0,qa1,qa2,qa3, qb0,qb1,qb2,qb3,
            f2a,f2b,f2c,f2d, f3a,f3b,f3c,f3d)
      STEPM((S-2-(i+7) > HS ? S-2-(i+7) : HS), (((i+3)&7)==7),
            qb0,qb1,qb2,qb3, qa0,qa1,qa2,qa3,
            f3a,f3b,f3c,f3d, f0a,f0b,f0c,f0d)
    }
    // tail STEPs (508..510), no rescale
    STEPM(HS, false, qa0,qa1,qa2,qa3, qb0,qb1,qb2,qb3,
          f0a,f0b,f0c,f0d, f1a,f1b,f1c,f1d)
    STEPM(HS, false, qb0,qb1,qb2,qb3, qa0,qa1,qa2,qa3,
          f1a,f1b,f1c,f1d, f2a,f2b,f2c,f2d)
    STEPM(HS, false, qa0,qa1,qa2,qa3, qb0,qb1,qb2,qb3,
          f2a,f2b,f2c,f2d, f3a,f3b,f3c,f3d)
    // bare final transform: w = E^T * frag(qb), packed raw
    {
      f16x8 B0 = u4f(qb0), B1 = u4f(qb1), B2 = u4f(qb2), B3 = u4f(qb3);
      f32x4 z = {0.f, 0.f, 0.f, 0.f};
      uint4 r0, r1, r2, r3;
#define MTRAW(AI, W0_, W1_)                                                    \
      {                                                                        \
        f32x4 p0 = MF(A[AI][0], B0, z);                                        \
        p0 = MF(A[AI][1], B1, p0);                                             \
        f32x4 p1 = MF(A[AI][2], B2, z);                                        \
        p1 = MF(A[AI][3], B3, p1);                                             \
        W0_ = pkrtz(p0[0] + p1[0], p0[1] + p1[1]);                             \
        W1_ = pkrtz(p0[2] + p1[2], p0[3] + p1[3]);                             \
      }
      MTRAW(0, r0.x, r0.y) MTRAW(1, r0.z, r0.w)
      MTRAW(2, r1.x, r1.y) MTRAW(3, r1.z, r1.w)
      MTRAW(4, r2.x, r2.y) MTRAW(5, r2.z, r2.w)
      MTRAW(6, r3.x, r3.y) MTRAW(7, r3.z, r3.w)
#undef MTRAW
      xw[l][0] = r0; xw[l][1] = r1; xw[l][2] = r2; xw[l][3] = r3;
      if (g == 0) xacc[c] = log2acc;
    }
  }
#undef STEPM
#undef PK2

  __syncthreads();

  if (wid == 0) {
    float d = 0.f;
    uint4 w0 = xw[l][0], w1 = xw[l][1], w2 = xw[l][2], w3 = xw[l][3];
    d += lo(qa0.x)*lo(w0.x) + hi(qa0.x)*hi(w0.x);
    d += lo(qa0.y)*lo(w0.y) + hi(qa0.y)*hi(w0.y);
    d += lo(qa0.z)*lo(w0.z) + hi(qa0.z)*hi(w0.z);
    d += lo(qa0.w)*lo(w0.w) + hi(qa0.w)*hi(w0.w);
    d += lo(qa1.x)*lo(w1.x) + hi(qa1.x)*hi(w1.x);
    d += lo(qa1.y)*lo(w1.y) + hi(qa1.y)*hi(w1.y);
    d += lo(qa1.z)*lo(w1.z) + hi(qa1.z)*hi(w1.z);
    d += lo(qa1.w)*lo(w1.w) + hi(qa1.w)*hi(w1.w);
    d += lo(qa2.x)*lo(w2.x) + hi(qa2.x)*hi(w2.x);
    d += lo(qa2.y)*lo(w2.y) + hi(qa2.y)*hi(w2.y);
    d += lo(qa2.z)*lo(w2.z) + hi(qa2.z)*hi(w2.z);
    d += lo(qa2.w)*lo(w2.w) + hi(qa2.w)*hi(w2.w);
    d += lo(qa3.x)*lo(w3.x) + hi(qa3.x)*hi(w3.x);
    d += lo(qa3.y)*lo(w3.y) + hi(qa3.y)*hi(w3.y);
    d += lo(qa3.z)*lo(w3.z) + hi(qa3.z)*hi(w3.z);
    d += lo(qa3.w)*lo(w3.w) + hi(qa3.w)*hi(w3.w);
    d += __shfl_xor(d, 16);
    d += __shfl_xor(d, 32);
    if (l < 16)
      out[b0 + l] =
          (lg2(fmaxf(d, 1e-30f)) + log2acc + xacc[l] + 8.0f * (float)S) * LN2;
  }
}

// ---- fallback (ws too small): round-7 kernel verbatim (known-pass)
__global__ __launch_bounds__(64, 1)
void crf_fused(const float* __restrict__ feats, const float* __restrict__ trans,
               float* __restrict__ out, int S) {
  const int l  = threadIdx.x;
  const int c  = l & 15;
  const int g  = l >> 4;
  const int b0 = blockIdx.x * NB;

  __shared__ __align__(16) unsigned char bufA[4096];
  __shared__ __align__(16) unsigned char bufB[4096];

  int wroff[8], rdoff[4];
#pragma unroll
  for (int mt = 0; mt < 8; ++mt)
    wroff[mt] = ((c << 8) + ((16 * mt + 4 * g) << 1)) ^ ((c & 7) << 4);
#pragma unroll
  for (int kk = 0; kk < 4; ++kk)
    rdoff[kk] = ((c << 8) + ((32 * kk + 8 * g) << 1)) ^ ((c & 7) << 4);

  f16x8 A[8][4];
#pragma unroll
  for (int mt = 0; mt < 8; ++mt) {
#pragma unroll
    for (int kk = 0; kk < 4; ++kk) {
      const float* r = trans + (size_t)(16 * mt + c) * T2 + 32 * kk + 8 * g;
      float4 u0 = *(const float4*)r;
      float4 u1 = *(const float4*)(r + 4);
      f16x8 a;
      a[0] = (f16)ex2(fmaf(u0.x, LOG2E, -8.f));
      a[1] = (f16)ex2(fmaf(u0.y, LOG2E, -8.f));
      a[2] = (f16)ex2(fmaf(u0.z, LOG2E, -8.f));
      a[3] = (f16)ex2(fmaf(u0.w, LOG2E, -8.f));
      a[4] = (f16)ex2(fmaf(u1.x, LOG2E, -8.f));
      a[5] = (f16)ex2(fmaf(u1.y, LOG2E, -8.f));
      a[6] = (f16)ex2(fmaf(u1.z, LOG2E, -8.f));
      a[7] = (f16)ex2(fmaf(u1.w, LOG2E, -8.f));
      A[mt][kk] = a;
    }
  }

#pragma unroll
  for (int i = 0; i < 4; ++i)
    *(uint4*)(bufA + l * 16 + i * 1024) = make_uint4(0, 0, 0, 0);
  if (l < 16)
    *(unsigned short*)(bufA + ((((l << 8) + 254)) ^ ((l & 7) << 4))) = 0x3C00;

  unsigned BX[16], BY[16];
#pragma unroll
  for (int kk = 0; kk < 4; ++kk) {
    uint4 u = *(const uint4*)(bufA + rdoff[kk]);
    BX[kk * 4 + 0] = u.x; BX[kk * 4 + 1] = u.y;
    BX[kk * 4 + 2] = u.z; BX[kk * 4 + 3] = u.w;
  }

  const float* fb = feats + ((size_t)(b0 + c) * S) * T2 + 4 * g;
  float4 PA[8], PB[8];
#pragma unroll
  for (int mt = 0; mt < 8; ++mt) PA[mt] = *(const float4*)(fb + 16 * mt);
#pragma unroll
  for (int mt = 0; mt < 8; ++mt) PB[mt] = *(const float4*)(fb + T2 + 16 * mt);
  unsigned EA[16], EB[16];
#pragma unroll
  for (int mt = 0; mt < 8; ++mt) {
    EA[2 * mt]     = pkrtz(ex2(PA[mt].x * LOG2E), ex2(PA[mt].y * LOG2E));
    EA[2 * mt + 1] = pkrtz(ex2(PA[mt].z * LOG2E), ex2(PA[mt].w * LOG2E));
  }

  float log2acc = 0.f;

#define FRAGF(B_, k_)                                                          \
  __builtin_bit_cast(f16x8, make_uint4(B_[4*(k_)], B_[4*(k_)+1],               \
                                       B_[4*(k_)+2], B_[4*(k_)+3]))

#define FBODY(T, BUFW, BIN, BOUT, PC, PN, EC, EN)                              \
  {                                                                            \
    const int t_ = (T);                                                        \
    {                                                                          \
      int tl = t_ + 2; if (tl > S - 1) tl = S - 1;                             \
      const float* fp_ = fb + (size_t)tl * T2;                                 \
      _Pragma("unroll")                                                        \
      for (int mt = 0; mt < 8; ++mt) PC[mt] = *(const float4*)(fp_ + 16 * mt); \
    }                                                                          \
    unsigned qd[16];                                                           \
    _Pragma("unroll")                                                          \
    for (int mt = 0; mt < 8; ++mt) {                                           \
      f32x4 acc = {0.f, 0.f, 0.f, 0.f};                                        \
      _Pragma("unroll")                                                        \
      for (int kk = 0; kk < 4; ++kk) {                                         \
        acc = __builtin_amdgcn_mfma_f32_16x16x32_f16(                          \
            A[mt][kk], FRAGF(BIN, kk), acc, 0, 0, 0);                          \
      }                                                                        \
      qd[2 * mt]     = pkmul(pkrtz(acc[0], acc[1]), EC[2 * mt]);               \
      qd[2 * mt + 1] = pkmul(pkrtz(acc[2], acc[3]), EC[2 * mt + 1]);           \
      *(uint2*)(BUFW + wroff[mt]) = make_uint2(qd[2 * mt], qd[2 * mt + 1]);    \
      if (mt & 1) {                                                            \
        uint4 u = *(const uint4*)(BUFW + rdoff[mt >> 1]);                      \
        BOUT[(mt >> 1) * 4 + 0] = u.x; BOUT[(mt >> 1) * 4 + 1] = u.y;          \
        BOUT[(mt >> 1) * 4 + 2] = u.z; BOUT[(mt >> 1) * 4 + 3] = u.w;          \
      }                                                                        \
    }                                                                          \
    _Pragma("unroll")                                                          \
    for (int mt = 0; mt < 8; ++mt) {                                           \
      EN[2 * mt]     = pkrtz(ex2(PN[mt].x * LOG2E), ex2(PN[mt].y * LOG2E));    \
      EN[2 * mt + 1] = pkrtz(ex2(PN[mt].z * LOG2E), ex2(PN[mt].w * LOG2E));    \
    }                                                                          \
    if (((t_ & 7) == 7) && (t_ != S - 1)) {                                    \
      f16x2 sv = __builtin_bit_cast(f16x2, qd[0]);                             \
      _Pragma("unroll")                                                        \
      for (int i = 1; i < 16; ++i) sv = sv + __builtin_bit_cast(f16x2, qd[i]); \
      float s_ = (float)sv.x + (float)sv.y;                                    \
      s_ += __shfl_xor(s_, 16);                                                \
      s_ += __shfl_xor(s_, 32);                                                \
      s_ = fmaxf(s_, 1e-4f);                                                   \
      float inv_ = 1.0f / s_;                                                  \
      unsigned ip_ = pkrtz(inv_, inv_);                                        \
      _Pragma("unroll")                                                        \
      for (int i = 0; i < 16; ++i) EN[i] = pkmul(EN[i], ip_);                  \
      log2acc += lg2(s_);                                                      \
    }                                                                          \
  }

  for (int t = 0; t < S; t += 2) {
    FBODY(t,     bufB, BX, BY, PA, PB, EA, EB)
    FBODY(t + 1, bufA, BY, BX, PB, PA, EB, EA)
  }
#undef FBODY
#undef FRAGF

  float p = 0.f;
#pragma unroll
  for (int kk = 0; kk < 4; ++kk) {
    const float* r = trans + (size_t)(T2 - 2) * T2 + 32 * kk + 8 * g;
    float4 u0 = *(const float4*)r;
    float4 u1 = *(const float4*)(r + 4);
    f16x2 h0 = __builtin_bit_cast(f16x2, BX[kk * 4 + 0]);
    f16x2 h1 = __builtin_bit_cast(f16x2, BX[kk * 4 + 1]);
    f16x2 h2 = __builtin_bit_cast(f16x2, BX[kk * 4 + 2]);
    f16x2 h3 = __builtin_bit_cast(f16x2, BX[kk * 4 + 3]);
    p += (float)h0.x * ex2(u0.x * LOG2E) + (float)h0.y * ex2(u0.y * LOG2E);
    p += (float)h1.x * ex2(u0.z * LOG2E) + (float)h1.y * ex2(u0.w * LOG2E);
    p += (float)h2.x * ex2(u1.x * LOG2E) + (float)h2.y * ex2(u1.y * LOG2E);
    p += (float)h3.x * ex2(u1.z * LOG2E) + (float)h3.y * ex2(u1.w * LOG2E);
  }
  p += __shfl_xor(p, 16);
  p += __shfl_xor(p, 32);
  if (l < 16)
    out[b0 + l] =
        (lg2(fmaxf(p, 1e-30f)) + log2acc + 8.0f * (float)S) * LN2;
}

extern "C" void kernel_launch(void* const* d_in, const int* in_sizes, int n_in,
                              void* d_out, int out_size, void* d_ws, size_t ws_size,
                              hipStream_t stream) {
  const float* feats = (const float*)d_in[0];
  const float* trans = (const float*)d_in[1];
  float* out = (float*)d_out;
  const int B = out_size;                // 256
  const int S = in_sizes[0] / (B * T2);  // 1024

  const size_t need = (size_t)B * S * T2 * 2;  // 64 MB f16 EF table
  if (d_ws && ws_size >= need && (S & 7) == 0) {
    unsigned* efp = (unsigned*)d_ws;
    long long n2 = (long long)B * S * 32;
    crf_expf<<<dim3((unsigned)((n2 + 255) / 256)), dim3(256), 0, stream>>>(feats, efp, n2);
    crf_scan<<<dim3(B / NB), dim3(128), 0, stream>>>(efp, trans, out, S);
  } else {
    crf_fused<<<dim3(B / NB), dim3(64), 0, stream>>>(feats, trans, out, S);
  }
}

// Round 17
// 259.117 us; speedup vs baseline: 1.2663x; 1.2663x over previous
//
#include <hip/hip_runtime.h>

#define T2 128
#define NB 16
#define LOG2E 1.44269504088896340736f
#define LN2   0.69314718055994530942f

typedef _Float16 f16;
typedef __attribute__((ext_vector_type(2))) _Float16 f16x2;
typedef __attribute__((ext_vector_type(8))) _Float16 f16x8;
typedef __attribute__((ext_vector_type(4))) float f32x4;

__device__ __forceinline__ unsigned pkrtz(float a, float b) {
  return __builtin_bit_cast(unsigned, __builtin_amdgcn_cvt_pkrtz(a, b));
}
__device__ __forceinline__ unsigned pkmul(unsigned a, unsigned b) {
  return __builtin_bit_cast(unsigned,
      (f16x2)(__builtin_bit_cast(f16x2, a) * __builtin_bit_cast(f16x2, b)));
}
__device__ __forceinline__ float ex2(float x) { return __builtin_amdgcn_exp2f(x); }
__device__ __forceinline__ float lg2(float x) { return __builtin_amdgcn_logf(x); }
__device__ __forceinline__ f16x8 u4f(uint4 u) { return __builtin_bit_cast(f16x8, u); }
__device__ __forceinline__ float lo(unsigned u) {
  return (float)__builtin_bit_cast(f16x2, u).x;
}
__device__ __forceinline__ float hi(unsigned u) {
  return (float)__builtin_bit_cast(f16x2, u).y;
}

// ---- kernel 1: exp pass, rho-permuted slot order (r12-validated).
__global__ __launch_bounds__(256)
void crf_expf(const float* __restrict__ feats, unsigned* __restrict__ efp,
              long long n2) {
  long long i = (long long)blockIdx.x * 256 + threadIdx.x;
  if (i >= n2) return;
  int r  = (int)(i & 31);
  int g  = r >> 3;
  int mt = r & 7;
  long long bt = i >> 5;  // b*S + t
  const float* f = feats + bt * T2 + 32 * (mt >> 1) + 8 * g + 4 * (mt & 1);
  float4 v = *(const float4*)f;
  uint2 o;
  o.x = pkrtz(ex2(v.x * LOG2E), ex2(v.y * LOG2E));
  o.y = pkrtz(ex2(v.z * LOG2E), ex2(v.w * LOG2E));
  *(uint2*)(efp + bt * 64 + 16 * g + 2 * mt) = o;
}

// ---- kernel 2: FORWARD-BACKWARD split (r14, best: 229us scan). 16 blocks
// x 128 threads (2 waves). Wave 0: q_512 forward over records 0..511.
// Wave 1: w_512 backward with E^T over records 1023..512. Z = w^T q.
// Exchange-free rho-closure per step (r12); waves independent until ONE
// end-of-kernel LDS exchange + barrier. A = exp2(trans*L2E - 8); +8*S at end.
// NOTE (r15/r16): k-major reorder and sched_group_barrier pinning BOTH
// regressed -- the compiler's natural schedule of this structure is the
// HIP-level optimum; do not re-fight it.
__global__ __launch_bounds__(128, 1)
void crf_scan(const unsigned* __restrict__ efp, const float* __restrict__ trans,
              float* __restrict__ out, int S) {
  const int tid = threadIdx.x;
  const int wid = tid >> 6;
  const int l   = tid & 63;
  const int c = l & 15, g = l >> 4;
  const int b0 = blockIdx.x * NB;
  const int HS = S >> 1;  // 512

  __shared__ uint4 xw[64][4];
  __shared__ float xacc[16];

  const unsigned* efb = efp + (size_t)(b0 + c) * S * 64 + (size_t)g * 16;

  f16x8 A[8][4];
  uint4 qa0, qa1, qa2, qa3;
  uint4 qb0 = make_uint4(0,0,0,0), qb1 = qb0, qb2 = qb0, qb3 = qb0;
  uint4 f0a, f0b, f0c, f0d, f1a, f1b, f1c, f1d;
  uint4 f2a, f2b, f2c, f2d, f3a, f3b, f3c, f3d;
  float log2acc = 0.f;

  if (wid == 0) {
    // forward A (rho rows, k cols raw), damped
#pragma unroll
    for (int mt = 0; mt < 8; ++mt) {
      const int prow = 32 * (mt >> 1) + 8 * (c >> 2) + 4 * (mt & 1) + (c & 3);
#pragma unroll
      for (int kk = 0; kk < 4; ++kk) {
        const float* r = trans + (size_t)prow * T2 + 32 * kk + 8 * g;
        float4 u0 = *(const float4*)r;
        float4 u1 = *(const float4*)(r + 4);
        f16x8 a;
        a[0] = (f16)ex2(fmaf(u0.x, LOG2E, -8.f));
        a[1] = (f16)ex2(fmaf(u0.y, LOG2E, -8.f));
        a[2] = (f16)ex2(fmaf(u0.z, LOG2E, -8.f));
        a[3] = (f16)ex2(fmaf(u0.w, LOG2E, -8.f));
        a[4] = (f16)ex2(fmaf(u1.x, LOG2E, -8.f));
        a[5] = (f16)ex2(fmaf(u1.y, LOG2E, -8.f));
        a[6] = (f16)ex2(fmaf(u1.z, LOG2E, -8.f));
        a[7] = (f16)ex2(fmaf(u1.w, LOG2E, -8.f));
        A[mt][kk] = a;
      }
    }
    qa0 = make_uint4(0,0,0,0); qa1 = qa0; qa2 = qa0; qa3 = qa0;
    qa3.w = (g == 3) ? 0x3C000000u : 0u;  // onehot at k=127
    f0a = *(const uint4*)(efb + 0);   f0b = *(const uint4*)(efb + 4);
    f0c = *(const uint4*)(efb + 8);   f0d = *(const uint4*)(efb + 12);
    f1a = *(const uint4*)(efb + 64);  f1b = *(const uint4*)(efb + 68);
    f1c = *(const uint4*)(efb + 72);  f1d = *(const uint4*)(efb + 76);
    f2a = *(const uint4*)(efb + 128); f2b = *(const uint4*)(efb + 132);
    f2c = *(const uint4*)(efb + 136); f2d = *(const uint4*)(efb + 140);
    f3a = *(const uint4*)(efb + 192); f3b = *(const uint4*)(efb + 196);
    f3c = *(const uint4*)(efb + 200); f3d = *(const uint4*)(efb + 204);
  } else {
    // backward A = E^T: element (prow, kcol) = exp2(trans[kcol][prow]*L2E-8)
#pragma unroll
    for (int mt = 0; mt < 8; ++mt) {
      const int prow = 32 * (mt >> 1) + 8 * (c >> 2) + 4 * (mt & 1) + (c & 3);
#pragma unroll
      for (int kk = 0; kk < 4; ++kk) {
        f16x8 a;
#pragma unroll
        for (int j = 0; j < 8; ++j)
          a[j] = (f16)ex2(fmaf(trans[(size_t)(32 * kk + 8 * g + j) * T2 + prow],
                               LOG2E, -8.f));
        A[mt][kk] = a;
      }
    }
    // initial frag = pk(eend) * EF[S-1]
    const float* te = trans + (size_t)(T2 - 2) * T2;
    const unsigned* e9 = efb + (size_t)(S - 1) * 64;
    uint4 E9a = *(const uint4*)(e9);     uint4 E9b = *(const uint4*)(e9 + 4);
    uint4 E9c = *(const uint4*)(e9 + 8); uint4 E9d = *(const uint4*)(e9 + 12);
#define EEW(kk, j2) pkrtz(ex2(te[32*(kk) + 8*g + 2*(j2)] * LOG2E),             \
                          ex2(te[32*(kk) + 8*g + 2*(j2) + 1] * LOG2E))
    qa0.x = pkmul(EEW(0,0), E9a.x); qa0.y = pkmul(EEW(0,1), E9a.y);
    qa0.z = pkmul(EEW(0,2), E9a.z); qa0.w = pkmul(EEW(0,3), E9a.w);
    qa1.x = pkmul(EEW(1,0), E9b.x); qa1.y = pkmul(EEW(1,1), E9b.y);
    qa1.z = pkmul(EEW(1,2), E9b.z); qa1.w = pkmul(EEW(1,3), E9b.w);
    qa2.x = pkmul(EEW(2,0), E9c.x); qa2.y = pkmul(EEW(2,1), E9c.y);
    qa2.z = pkmul(EEW(2,2), E9c.z); qa2.w = pkmul(EEW(2,3), E9c.w);
    qa3.x = pkmul(EEW(3,0), E9d.x); qa3.y = pkmul(EEW(3,1), E9d.y);
    qa3.z = pkmul(EEW(3,2), E9d.z); qa3.w = pkmul(EEW(3,3), E9d.w);
#undef EEW
    const unsigned* p0 = efb + (size_t)(S - 2) * 64;
    const unsigned* p1 = efb + (size_t)(S - 3) * 64;
    const unsigned* p2 = efb + (size_t)(S - 4) * 64;
    const unsigned* p3 = efb + (size_t)(S - 5) * 64;
    f0a = *(const uint4*)(p0); f0b = *(const uint4*)(p0+4);
    f0c = *(const uint4*)(p0+8); f0d = *(const uint4*)(p0+12);
    f1a = *(const uint4*)(p1); f1b = *(const uint4*)(p1+4);
    f1c = *(const uint4*)(p1+8); f1d = *(const uint4*)(p1+12);
    f2a = *(const uint4*)(p2); f2b = *(const uint4*)(p2+4);
    f2c = *(const uint4*)(p2+8); f2d = *(const uint4*)(p2+12);
    f3a = *(const uint4*)(p3); f3b = *(const uint4*)(p3+4);
    f3c = *(const uint4*)(p3+8); f3d = *(const uint4*)(p3+12);
  }

#define MT(AI, B0_, B1_, B2_, B3_, W0_, W1_, E0_, E1_)                         \
  {                                                                            \
    f32x4 z = {0.f, 0.f, 0.f, 0.f};                                            \
    f32x4 p0 = __builtin_amdgcn_mfma_f32_16x16x32_f16(A[AI][0], B0_, z, 0, 0, 0); \
    p0 = __builtin_amdgcn_mfma_f32_16x16x32_f16(A[AI][1], B1_, p0, 0, 0, 0);   \
    f32x4 p1 = __builtin_amdgcn_mfma_f32_16x16x32_f16(A[AI][2], B2_, z, 0, 0, 0); \
    p1 = __builtin_amdgcn_mfma_f32_16x16x32_f16(A[AI][3], B3_, p1, 0, 0, 0);   \
    W0_ = pkmul(pkrtz(p0[0] + p1[0], p0[1] + p1[1]), E0_);                     \
    W1_ = pkmul(pkrtz(p0[2] + p1[2], p0[3] + p1[3]), E1_);                     \
  }
#define MTRAW(AI, B0_, B1_, B2_, B3_, W0_, W1_)                                \
  {                                                                            \
    f32x4 z = {0.f, 0.f, 0.f, 0.f};                                            \
    f32x4 p0 = __builtin_amdgcn_mfma_f32_16x16x32_f16(A[AI][0], B0_, z, 0, 0, 0); \
    p0 = __builtin_amdgcn_mfma_f32_16x16x32_f16(A[AI][1], B1_, p0, 0, 0, 0);   \
    f32x4 p1 = __builtin_amdgcn_mfma_f32_16x16x32_f16(A[AI][2], B2_, z, 0, 0, 0); \
    p1 = __builtin_amdgcn_mfma_f32_16x16x32_f16(A[AI][3], B3_, p1, 0, 0, 0);   \
    W0_ = pkrtz(p0[0] + p1[0], p0[1] + p1[1]);                                 \
    W1_ = pkrtz(p0[2] + p1[2], p0[3] + p1[3]);                                 \
  }

#define STEPM(RELREC, DORESC, P0,P1,P2,P3, N0,N1,N2,N3, CA,CB,CC,CD,           \
              GA,GB,GC,GD)                                                     \
  {                                                                            \
    f16x8 B0 = u4f(P0), B1 = u4f(P1), B2 = u4f(P2), B3 = u4f(P3);              \
    MT(0, B0, B1, B2, B3, N0.x, N0.y, CA.x, CA.y)                              \
    MT(1, B0, B1, B2, B3, N0.z, N0.w, CA.z, CA.w)                              \
    MT(2, B0, B1, B2, B3, N1.x, N1.y, CB.x, CB.y)                              \
    MT(3, B0, B1, B2, B3, N1.z, N1.w, CB.z, CB.w)                              \
    MT(4, B0, B1, B2, B3, N2.x, N2.y, CC.x, CC.y)                              \
    MT(5, B0, B1, B2, B3, N2.z, N2.w, CC.z, CC.w)                              \
    MT(6, B0, B1, B2, B3, N3.x, N3.y, CD.x, CD.y)                              \
    MT(7, B0, B1, B2, B3, N3.z, N3.w, CD.z, CD.w)                              \
    {                                                                          \
      const unsigned* p_ = efb + (size_t)(RELREC) * 64;                        \
      CA = *(const uint4*)(p_);      CB = *(const uint4*)(p_ + 4);             \
      CC = *(const uint4*)(p_ + 8);  CD = *(const uint4*)(p_ + 12);            \
    }                                                                          \
    if (DORESC) {                                                              \
      float s_ = lo(N0.x) + hi(N0.x) + lo(N0.y) + hi(N0.y)                     \
               + lo(N0.z) + hi(N0.z) + lo(N0.w) + hi(N0.w)                     \
               + lo(N1.x) + hi(N1.x) + lo(N1.y) + hi(N1.y)                     \
               + lo(N1.z) + hi(N1.z) + lo(N1.w) + hi(N1.w)                     \
               + lo(N2.x) + hi(N2.x) + lo(N2.y) + hi(N2.y)                     \
               + lo(N2.z) + hi(N2.z) + lo(N2.w) + hi(N2.w)                     \
               + lo(N3.x) + hi(N3.x) + lo(N3.y) + hi(N3.y)                     \
               + lo(N3.z) + hi(N3.z) + lo(N3.w) + hi(N3.w);                    \
      s_ += __shfl_xor(s_, 16);                                                \
      s_ += __shfl_xor(s_, 32);                                                \
      s_ = fmaxf(s_, 1e-30f);                                                  \
      float inv_ = 1.0f / s_;                                                  \
      unsigned ip_ = pkrtz(inv_, inv_);                                        \
      GA.x = pkmul(GA.x, ip_); GA.y = pkmul(GA.y, ip_);                        \
      GA.z = pkmul(GA.z, ip_); GA.w = pkmul(GA.w, ip_);                        \
      GB.x = pkmul(GB.x, ip_); GB.y = pkmul(GB.y, ip_);                        \
      GB.z = pkmul(GB.z, ip_); GB.w = pkmul(GB.w, ip_);                        \
      GC.x = pkmul(GC.x, ip_); GC.y = pkmul(GC.y, ip_);                        \
      GC.z = pkmul(GC.z, ip_); GC.w = pkmul(GC.w, ip_);                        \
      GD.x = pkmul(GD.x, ip_); GD.y = pkmul(GD.y, ip_);                        \
      GD.z = pkmul(GD.z, ip_); GD.w = pkmul(GD.w, ip_);                        \
      log2acc += lg2(s_);                                                      \
    }                                                                          \
  }

  if (wid == 0) {
    for (int t = 0; t < HS; t += 4) {
      STEPM((t+4 < HS ? t+4 : HS-1), ((t&7)==7),
            qa0,qa1,qa2,qa3, qb0,qb1,qb2,qb3,
            f0a,f0b,f0c,f0d, f1a,f1b,f1c,f1d)
      STEPM((t+5 < HS ? t+5 : HS-1), (((t+1)&7)==7),
            qb0,qb1,qb2,qb3, qa0,qa1,qa2,qa3,
            f1a,f1b,f1c,f1d, f2a,f2b,f2c,f2d)
      STEPM((t+6 < HS ? t+6 : HS-1), (((t+2)&7)==7),
            qa0,qa1,qa2,qa3, qb0,qb1,qb2,qb3,
            f2a,f2b,f2c,f2d, f3a,f3b,f3c,f3d)
      STEPM((t+7 < HS ? t+7 : HS-1), (((t+3)&7)==7 && t+3 != HS-1),
            qb0,qb1,qb2,qb3, qa0,qa1,qa2,qa3,
            f3a,f3b,f3c,f3d, f0a,f0b,f0c,f0d)
    }
  } else {
    for (int i = 0; i + 4 <= HS - 1; i += 4) {
      STEPM((S-2-(i+4) > HS ? S-2-(i+4) : HS), ((i&7)==7),
            qa0,qa1,qa2,qa3, qb0,qb1,qb2,qb3,
            f0a,f0b,f0c,f0d, f1a,f1b,f1c,f1d)
      STEPM((S-2-(i+5) > HS ? S-2-(i+5) : HS), (((i+1)&7)==7),
            qb0,qb1,qb2,qb3, qa0,qa1,qa2,qa3,
            f1a,f1b,f1c,f1d, f2a,f2b,f2c,f2d)
      STEPM((S-2-(i+6) > HS ? S-2-(i+6) : HS), (((i+2)&7)==7),
            qa0,qa1,qa2,qa3, qb0,qb1,qb2,qb3,
            f2a,f2b,f2c,f2d, f3a,f3b,f3c,f3d)
      STEPM((S-2-(i+7) > HS ? S-2-(i+7) : HS), (((i+3)&7)==7),
            qb0,qb1,qb2,qb3, qa0,qa1,qa2,qa3,
            f3a,f3b,f3c,f3d, f0a,f0b,f0c,f0d)
    }
    // tail STEPs (508..510), no rescale
    STEPM(HS, false, qa0,qa1,qa2,qa3, qb0,qb1,qb2,qb3,
          f0a,f0b,f0c,f0d, f1a,f1b,f1c,f1d)
    STEPM(HS, false, qb0,qb1,qb2,qb3, qa0,qa1,qa2,qa3,
          f1a,f1b,f1c,f1d, f2a,f2b,f2c,f2d)
    STEPM(HS, false, qa0,qa1,qa2,qa3, qb0,qb1,qb2,qb3,
          f2a,f2b,f2c,f2d, f3a,f3b,f3c,f3d)
    // bare final transform: w = E^T * frag(qb), packed raw
    {
      f16x8 B0 = u4f(qb0), B1 = u4f(qb1), B2 = u4f(qb2), B3 = u4f(qb3);
      uint4 r0, r1, r2, r3;
      MTRAW(0, B0, B1, B2, B3, r0.x, r0.y)
      MTRAW(1, B0, B1, B2, B3, r0.z, r0.w)
      MTRAW(2, B0, B1, B2, B3, r1.x, r1.y)
      MTRAW(3, B0, B1, B2, B3, r1.z, r1.w)
      MTRAW(4, B0, B1, B2, B3, r2.x, r2.y)
      MTRAW(5, B0, B1, B2, B3, r2.z, r2.w)
      MTRAW(6, B0, B1, B2, B3, r3.x, r3.y)
      MTRAW(7, B0, B1, B2, B3, r3.z, r3.w)
      xw[l][0] = r0; xw[l][1] = r1; xw[l][2] = r2; xw[l][3] = r3;
      if (g == 0) xacc[c] = log2acc;
    }
  }
#undef STEPM
#undef MTRAW
#undef MT

  __syncthreads();

  if (wid == 0) {
    float d = 0.f;
    uint4 w0 = xw[l][0], w1 = xw[l][1], w2 = xw[l][2], w3 = xw[l][3];
    d += lo(qa0.x)*lo(w0.x) + hi(qa0.x)*hi(w0.x);
    d += lo(qa0.y)*lo(w0.y) + hi(qa0.y)*hi(w0.y);
    d += lo(qa0.z)*lo(w0.z) + hi(qa0.z)*hi(w0.z);
    d += lo(qa0.w)*lo(w0.w) + hi(qa0.w)*hi(w0.w);
    d += lo(qa1.x)*lo(w1.x) + hi(qa1.x)*hi(w1.x);
    d += lo(qa1.y)*lo(w1.y) + hi(qa1.y)*hi(w1.y);
    d += lo(qa1.z)*lo(w1.z) + hi(qa1.z)*hi(w1.z);
    d += lo(qa1.w)*lo(w1.w) + hi(qa1.w)*hi(w1.w);
    d += lo(qa2.x)*lo(w2.x) + hi(qa2.x)*hi(w2.x);
    d += lo(qa2.y)*lo(w2.y) + hi(qa2.y)*hi(w2.y);
    d += lo(qa2.z)*lo(w2.z) + hi(qa2.z)*hi(w2.z);
    d += lo(qa2.w)*lo(w2.w) + hi(qa2.w)*hi(w2.w);
    d += lo(qa3.x)*lo(w3.x) + hi(qa3.x)*hi(w3.x);
    d += lo(qa3.y)*lo(w3.y) + hi(qa3.y)*hi(w3.y);
    d += lo(qa3.z)*lo(w3.z) + hi(qa3.z)*hi(w3.z);
    d += lo(qa3.w)*lo(w3.w) + hi(qa3.w)*hi(w3.w);
    d += __shfl_xor(d, 16);
    d += __shfl_xor(d, 32);
    if (l < 16)
      out[b0 + l] =
          (lg2(fmaxf(d, 1e-30f)) + log2acc + xacc[l] + 8.0f * (float)S) * LN2;
  }
}

// ---- fallback (ws too small): round-7 kernel verbatim (known-pass)
__global__ __launch_bounds__(64, 1)
void crf_fused(const float* __restrict__ feats, const float* __restrict__ trans,
               float* __restrict__ out, int S) {
  const int l  = threadIdx.x;
  const int c  = l & 15;
  const int g  = l >> 4;
  const int b0 = blockIdx.x * NB;

  __shared__ __align__(16) unsigned char bufA[4096];
  __shared__ __align__(16) unsigned char bufB[4096];

  int wroff[8], rdoff[4];
#pragma unroll
  for (int mt = 0; mt < 8; ++mt)
    wroff[mt] = ((c << 8) + ((16 * mt + 4 * g) << 1)) ^ ((c & 7) << 4);
#pragma unroll
  for (int kk = 0; kk < 4; ++kk)
    rdoff[kk] = ((c << 8) + ((32 * kk + 8 * g) << 1)) ^ ((c & 7) << 4);

  f16x8 A[8][4];
#pragma unroll
  for (int mt = 0; mt < 8; ++mt) {
#pragma unroll
    for (int kk = 0; kk < 4; ++kk) {
      const float* r = trans + (size_t)(16 * mt + c) * T2 + 32 * kk + 8 * g;
      float4 u0 = *(const float4*)r;
      float4 u1 = *(const float4*)(r + 4);
      f16x8 a;
      a[0] = (f16)ex2(fmaf(u0.x, LOG2E, -8.f));
      a[1] = (f16)ex2(fmaf(u0.y, LOG2E, -8.f));
      a[2] = (f16)ex2(fmaf(u0.z, LOG2E, -8.f));
      a[3] = (f16)ex2(fmaf(u0.w, LOG2E, -8.f));
      a[4] = (f16)ex2(fmaf(u1.x, LOG2E, -8.f));
      a[5] = (f16)ex2(fmaf(u1.y, LOG2E, -8.f));
      a[6] = (f16)ex2(fmaf(u1.z, LOG2E, -8.f));
      a[7] = (f16)ex2(fmaf(u1.w, LOG2E, -8.f));
      A[mt][kk] = a;
    }
  }

#pragma unroll
  for (int i = 0; i < 4; ++i)
    *(uint4*)(bufA + l * 16 + i * 1024) = make_uint4(0, 0, 0, 0);
  if (l < 16)
    *(unsigned short*)(bufA + ((((l << 8) + 254)) ^ ((l & 7) << 4))) = 0x3C00;

  unsigned BX[16], BY[16];
#pragma unroll
  for (int kk = 0; kk < 4; ++kk) {
    uint4 u = *(const uint4*)(bufA + rdoff[kk]);
    BX[kk * 4 + 0] = u.x; BX[kk * 4 + 1] = u.y;
    BX[kk * 4 + 2] = u.z; BX[kk * 4 + 3] = u.w;
  }

  const float* fb = feats + ((size_t)(b0 + c) * S) * T2 + 4 * g;
  float4 PA[8], PB[8];
#pragma unroll
  for (int mt = 0; mt < 8; ++mt) PA[mt] = *(const float4*)(fb + 16 * mt);
#pragma unroll
  for (int mt = 0; mt < 8; ++mt) PB[mt] = *(const float4*)(fb + T2 + 16 * mt);
  unsigned EA[16], EB[16];
#pragma unroll
  for (int mt = 0; mt < 8; ++mt) {
    EA[2 * mt]     = pkrtz(ex2(PA[mt].x * LOG2E), ex2(PA[mt].y * LOG2E));
    EA[2 * mt + 1] = pkrtz(ex2(PA[mt].z * LOG2E), ex2(PA[mt].w * LOG2E));
  }

  float log2acc = 0.f;

#define FRAGF(B_, k_)                                                          \
  __builtin_bit_cast(f16x8, make_uint4(B_[4*(k_)], B_[4*(k_)+1],               \
                                       B_[4*(k_)+2], B_[4*(k_)+3]))

#define FBODY(T, BUFW, BIN, BOUT, PC, PN, EC, EN)                              \
  {                                                                            \
    const int t_ = (T);                                                        \
    {                                                                          \
      int tl = t_ + 2; if (tl > S - 1) tl = S - 1;                             \
      const float* fp_ = fb + (size_t)tl * T2;                                 \
      _Pragma("unroll")                                                        \
      for (int mt = 0; mt < 8; ++mt) PC[mt] = *(const float4*)(fp_ + 16 * mt); \
    }                                                                          \
    unsigned qd[16];                                                           \
    _Pragma("unroll")                                                          \
    for (int mt = 0; mt < 8; ++mt) {                                           \
      f32x4 acc = {0.f, 0.f, 0.f, 0.f};                                        \
      _Pragma("unroll")                                                        \
      for (int kk = 0; kk < 4; ++kk) {                                         \
        acc = __builtin_amdgcn_mfma_f32_16x16x32_f16(                          \
            A[mt][kk], FRAGF(BIN, kk), acc, 0, 0, 0);                          \
      }                                                                        \
      qd[2 * mt]     = pkmul(pkrtz(acc[0], acc[1]), EC[2 * mt]);               \
      qd[2 * mt + 1] = pkmul(pkrtz(acc[2], acc[3]), EC[2 * mt + 1]);           \
      *(uint2*)(BUFW + wroff[mt]) = make_uint2(qd[2 * mt], qd[2 * mt + 1]);    \
      if (mt & 1) {                                                            \
        uint4 u = *(const uint4*)(BUFW + rdoff[mt >> 1]);                      \
        BOUT[(mt >> 1) * 4 + 0] = u.x; BOUT[(mt >> 1) * 4 + 1] = u.y;          \
        BOUT[(mt >> 1) * 4 + 2] = u.z; BOUT[(mt >> 1) * 4 + 3] = u.w;          \
      }                                                                        \
    }                                                                          \
    _Pragma("unroll")                                                          \
    for (int mt = 0; mt < 8; ++mt) {                                           \
      EN[2 * mt]     = pkrtz(ex2(PN[mt].x * LOG2E), ex2(PN[mt].y * LOG2E));    \
      EN[2 * mt + 1] = pkrtz(ex2(PN[mt].z * LOG2E), ex2(PN[mt].w * LOG2E));    \
    }                                                                          \
    if (((t_ & 7) == 7) && (t_ != S - 1)) {                                    \
      f16x2 sv = __builtin_bit_cast(f16x2, qd[0]);                             \
      _Pragma("unroll")                                                        \
      for (int i = 1; i < 16; ++i) sv = sv + __builtin_bit_cast(f16x2, qd[i]); \
      float s_ = (float)sv.x + (float)sv.y;                                    \
      s_ += __shfl_xor(s_, 16);                                                \
      s_ += __shfl_xor(s_, 32);                                                \
      s_ = fmaxf(s_, 1e-4f);                                                   \
      float inv_ = 1.0f / s_;                                                  \
      unsigned ip_ = pkrtz(inv_, inv_);                                        \
      _Pragma("unroll")                                                        \
      for (int i = 0; i < 16; ++i) EN[i] = pkmul(EN[i], ip_);                  \
      log2acc += lg2(s_);                                                      \
    }                                                                          \
  }

  for (int t = 0; t < S; t += 2) {
    FBODY(t,     bufB, BX, BY, PA, PB, EA, EB)
    FBODY(t + 1, bufA, BY, BX, PB, PA, EB, EA)
  }
#undef FBODY
#undef FRAGF

  float p = 0.f;
#pragma unroll
  for (int kk = 0; kk < 4; ++kk) {
    const float* r = trans + (size_t)(T2 - 2) * T2 + 32 * kk + 8 * g;
    float4 u0 = *(const float4*)r;
    float4 u1 = *(const float4*)(r + 4);
    f16x2 h0 = __builtin_bit_cast(f16x2, BX[kk * 4 + 0]);
    f16x2 h1 = __builtin_bit_cast(f16x2, BX[kk * 4 + 1]);
    f16x2 h2 = __builtin_bit_cast(f16x2, BX[kk * 4 + 2]);
    f16x2 h3 = __builtin_bit_cast(f16x2, BX[kk * 4 + 3]);
    p += (float)h0.x * ex2(u0.x * LOG2E) + (float)h0.y * ex2(u0.y * LOG2E);
    p += (float)h1.x * ex2(u0.z * LOG2E) + (float)h1.y * ex2(u0.w * LOG2E);
    p += (float)h2.x * ex2(u1.x * LOG2E) + (float)h2.y * ex2(u1.y * LOG2E);
    p += (float)h3.x * ex2(u1.z * LOG2E) + (float)h3.y * ex2(u1.w * LOG2E);
  }
  p += __shfl_xor(p, 16);
  p += __shfl_xor(p, 32);
  if (l < 16)
    out[b0 + l] =
        (lg2(fmaxf(p, 1e-30f)) + log2acc + 8.0f * (float)S) * LN2;
}

extern "C" void kernel_launch(void* const* d_in, const int* in_sizes, int n_in,
                              void* d_out, int out_size, void* d_ws, size_t ws_size,
                              hipStream_t stream) {
  const float* feats = (const float*)d_in[0];
  const float* trans = (const float*)d_in[1];
  float* out = (float*)d_out;
  const int B = out_size;                // 256
  const int S = in_sizes[0] / (B * T2);  // 1024

  const size_t need = (size_t)B * S * T2 * 2;  // 64 MB f16 EF table
  if (d_ws && ws_size >= need && (S & 7) == 0) {
    unsigned* efp = (unsigned*)d_ws;
    long long n2 = (long long)B * S * 32;
    crf_expf<<<dim3((unsigned)((n2 + 255) / 256)), dim3(256), 0, stream>>>(feats, efp, n2);
    crf_scan<<<dim3(B / NB), dim3(128), 0, stream>>>(efp, trans, out, S);
  } else {
    crf_fused<<<dim3(B / NB), dim3(64), 0, stream>>>(feats, trans, out, S);
  }
}